// Round 10
// baseline (506.392 us; speedup 1.0000x reference)
//
#include <hip/hip_runtime.h>
#include <math.h>

__device__ __forceinline__ float rho(float s) { return fminf(fmaxf(s, 0.f), 1.f); }
// d/ds clip(s,0,1) with JAX maximum/minimum tie-gradient = 0.5
__device__ __forceinline__ float drho(float s) {
  if (s < 0.f || s > 1.f) return 0.f;
  float g = 1.f;
  if (s == 0.f) g *= 0.5f;
  if (s == 1.f) g *= 0.5f;
  return g;
}

// v += CTRL-shifted v within 16-lane DPP row; bound_ctrl -> 0 fill.
// row_shr moves data toward HIGHER lanes: complete 16-sum lands in lane 15.
template <int CTRL>
__device__ __forceinline__ float dpp_add(float v) {
  const int x =
      __builtin_amdgcn_update_dpp(0, __float_as_int(v), CTRL, 0xf, 0xf, true);
  return v + __int_as_float(x);
}
__device__ __forceinline__ float dpp_reduce16(float v) {
  v = dpp_add<0x118>(v);  // row_shr:8
  v = dpp_add<0x114>(v);  // row_shr:4
  v = dpp_add<0x112>(v);  // row_shr:2
  v = dpp_add<0x111>(v);  // row_shr:1  -> lane rr==15 holds the 16-sum
  return v;
}

// ---------------- Phase A: per-block partials of c0 = rho(x) @ W0 ----------
// First 128 blocks also touch 4 KB of W1 each (kept live via empty asm) so
// W1 is L3-resident when the single-CU k2 loads it.
template <int ROWS>
__global__ __launch_bounds__(256) void k1_xw0(const float* __restrict__ x,
                                              const float* __restrict__ W0,
                                              const float* __restrict__ W1,
                                              float* __restrict__ part) {
  __shared__ float xs[ROWS];
  __shared__ float red[8][132];
  const int t = threadIdx.x;
  const int b = blockIdx.x;
  if (b < 128) {  // W1 prefetch into L3: 128 blk x 256 thr x 16 B = 512 KB
    const float4 v =
        reinterpret_cast<const float4*>(W1)[b * 256 + t];
    float sv = (v.x + v.y) + (v.z + v.w);
    asm volatile("" ::"v"(sv));  // keep load alive, no store (rule #17)
  }
  const int r0 = b * ROWS;
  for (int i = t; i < ROWS; i += 256) xs[i] = rho(x[r0 + i]);
  __syncthreads();
  const int cq = t & 31;
  const int rg = t >> 5;
  constexpr int GR = ROWS / 8;
  const float4* __restrict__ W4 = reinterpret_cast<const float4*>(W0);
  float ax = 0.f, ay = 0.f, az = 0.f, aw = 0.f;
  const int base = (r0 + rg * GR) * 32 + cq;
#pragma unroll 8
  for (int i = 0; i < GR; ++i) {
    const float xv = xs[rg * GR + i];
    const float4 w = W4[base + i * 32];
    ax = fmaf(xv, w.x, ax);
    ay = fmaf(xv, w.y, ay);
    az = fmaf(xv, w.z, az);
    aw = fmaf(xv, w.w, aw);
  }
  red[rg][cq * 4 + 0] = ax;
  red[rg][cq * 4 + 1] = ay;
  red[rg][cq * 4 + 2] = az;
  red[rg][cq * 4 + 3] = aw;
  __syncthreads();
  if (t < 128) {
    float s = 0.f;
#pragma unroll
    for (int g = 0; g < 8; ++g) s += red[g][t];
    part[b * 128 + t] = s;
  }
}

// ---------------- Phase A2: tree-reduce part1 (nblk x 128) -> part2 --------
__global__ __launch_bounds__(256) void k1b_reduce(const float* __restrict__ part1,
                                                  float* __restrict__ part2) {
  __shared__ float acc[2][128];
  const int t = threadIdx.x, i = blockIdx.x;
  const int jk = t & 127, half = t >> 7;
  float s = 0.f;
  const int r0 = i * 32 + half * 16;
#pragma unroll
  for (int r = 0; r < 16; ++r) s += part1[(r0 + r) * 128 + jk];
  acc[half][jk] = s;
  __syncthreads();
  if (half == 0) part2[i * 128 + jk] = acc[0][jk] + acc[1][jk];
}

// ---------------- Phase B: ONE workgroup of 256 threads (4 waves) -----------
// 1 wave/SIMD -> full 512-reg unified VGPR+AGPR file per wave (r8/r9 lesson:
// 512 threads = 2 waves/SIMD caps at 256 and the 192-float tile spilled to
// scratch). Thread (rr,cg), rr=lane&15, cg=wave*4+(lane>>4):
//   - 8 rows [8rr..8rr+8) x 48 reg cols [48cg..) of [0,768): 384 W regs
//   - 16 LDS cols 768+[16cg..): slot-permuted+XOR-swizzled, 128 KB
// Per iter: fused pass computes b=W1^T rh (DPP row-reduce) and pa=W1 ro
// (staged via ap_). 2 __syncthreads/iter. Zero inter-block traffic.
__global__ __launch_bounds__(256, 1)
void k2_iter(const float* __restrict__ part2,
             const int npart2,
             const float* __restrict__ W1,
             const float* __restrict__ b1,
             const float* __restrict__ b2,
             const int* __restrict__ niterp,
             float* __restrict__ out) {
  __shared__ float wlds[256 * 128];  // 128 KB, col-major slots, XOR-swizzled
  __shared__ float ro_[1024];
  __shared__ float rh_[128];
  __shared__ float bl_[1024];
  __shared__ float ap_[16][132];     // a-partials per col-group

  const int t = threadIdx.x;
  const int lane = t & 63;
  const int wv = t >> 6;
  const int rr = lane & 15;             // rows [8rr, 8rr+8)
  const int cg = wv * 4 + (lane >> 4);  // col group in [0,16)
  const int RC = cg * 48;               // reg-col base
  const int LCl = cg * 16;              // lds-col base (local, 0..255)

  // ---- load reg tile W[8rr..+8][RC..RC+48): 384 VGPRs, static-indexed ----
  float w[384];
#pragma unroll
  for (int r = 0; r < 8; ++r) {
    const float4* gr =
        reinterpret_cast<const float4*>(W1 + (8 * rr + r) * 1024 + RC);
#pragma unroll
    for (int i = 0; i < 12; ++i) {
      const float4 v = gr[i];
      w[r * 48 + 4 * i + 0] = v.x;
      w[r * 48 + 4 * i + 1] = v.y;
      w[r * 48 + 4 * i + 2] = v.z;
      w[r * 48 + 4 * i + 3] = v.w;
    }
  }
  // ---- stage cols 768..1023 into LDS ----
  // local col k -> slot s = ((k&7)<<5) + ((k>>4)<<1) + ((k>>3)&1)
  //   (same-cg cols -> 32-apart slots; s&7 differs across a wave's 4 cgs)
  // element (j,k) at wlds[s*128 + (((j>>2)^(s&7))<<2) + (j&3)]
  {
    const int j = t >> 1;                 // row 0..127
    const int ch = t & 1;                 // col half
#pragma unroll
    for (int i = 0; i < 32; ++i) {
      const float4 v = *reinterpret_cast<const float4*>(
          W1 + j * 1024 + 768 + ch * 128 + 4 * i);
#pragma unroll
      for (int q = 0; q < 4; ++q) {
        const int k = ch * 128 + 4 * i + q;
        const int s = ((k & 7) << 5) + ((k >> 4) << 1) + ((k >> 3) & 1);
        wlds[s * 128 + (((j >> 2) ^ (s & 7)) << 2) + (j & 3)] = (&v.x)[q];
      }
    }
  }
  // ---- init: c0 (t<128), biases, zero state ----
  float c0v = 0.f, b1v = 0.f, hreg = 0.f, mh = 0.f, vh = 0.f;
  if (t < 128) {
    if (npart2 == 32) {  // fast path: 32 independent loads, one latency round
      float s0 = 0.f, s1 = 0.f, s2 = 0.f, s3 = 0.f;
#pragma unroll
      for (int r = 0; r < 32; r += 4) {
        s0 += part2[(r + 0) * 128 + t];
        s1 += part2[(r + 1) * 128 + t];
        s2 += part2[(r + 2) * 128 + t];
        s3 += part2[(r + 3) * 128 + t];
      }
      c0v = (s0 + s1) + (s2 + s3);
    } else {
      float s0 = 0.f;
#pragma unroll 4
      for (int r = 0; r < npart2; ++r) s0 += part2[r * 128 + t];
      c0v = s0;
    }
    b1v = b1[t];
    rh_[t] = 0.f;
  }
  float ov[4], mo[4], vo[4], b2v[4];
#pragma unroll
  for (int q = 0; q < 4; ++q) {
    ov[q] = 0.f; mo[q] = 0.f; vo[q] = 0.f;
    b2v[q] = b2[t + 256 * q];
    ro_[t + 256 * q] = 0.f;
  }
  const int niter = *niterp;
  float pw1 = 1.f, pw2 = 1.f;
  __syncthreads();

  for (int it = 1; it <= niter; ++it) {
    pw1 *= 0.9f;
    pw2 *= 0.999f;
    const float bc1 = 1.f - pw1, bc2 = 1.f - pw2;
    // rh for own 8 rows
    float rh8[8];
    {
      const float4 ra = *reinterpret_cast<const float4*>(&rh_[8 * rr]);
      const float4 rb = *reinterpret_cast<const float4*>(&rh_[8 * rr + 4]);
      rh8[0] = ra.x; rh8[1] = ra.y; rh8[2] = ra.z; rh8[3] = ra.w;
      rh8[4] = rb.x; rh8[5] = rb.y; rh8[6] = rb.z; rh8[7] = rb.w;
    }
    float pa[8] = {0.f, 0.f, 0.f, 0.f, 0.f, 0.f, 0.f, 0.f};
    // ---- reg cols: 6 sub-passes of 8 cols ----
#pragma unroll
    for (int sp = 0; sp < 6; ++sp) {
      float bacc[8] = {0.f, 0.f, 0.f, 0.f, 0.f, 0.f, 0.f, 0.f};
      const float4 ra = *reinterpret_cast<const float4*>(&ro_[RC + sp * 8]);
      const float4 rb = *reinterpret_cast<const float4*>(&ro_[RC + sp * 8 + 4]);
#pragma unroll
      for (int q = 0; q < 8; ++q) {
        const float roc = (q < 4) ? (&ra.x)[q] : (&rb.x)[q - 4];
        const int c = sp * 8 + q;
#pragma unroll
        for (int r = 0; r < 8; ++r) {
          const float we = w[r * 48 + c];
          bacc[q] = fmaf(rh8[r], we, bacc[q]);
          pa[r] = fmaf(we, roc, pa[r]);
        }
      }
#pragma unroll
      for (int q = 0; q < 8; ++q) bacc[q] = dpp_reduce16(bacc[q]);
      if (rr == 15) {
        *reinterpret_cast<float4*>(&bl_[RC + sp * 8]) =
            make_float4(bacc[0], bacc[1], bacc[2], bacc[3]);
        *reinterpret_cast<float4*>(&bl_[RC + sp * 8 + 4]) =
            make_float4(bacc[4], bacc[5], bacc[6], bacc[7]);
      }
    }
    // ---- LDS cols: 2 sub-passes of 8 cols ----
#pragma unroll
    for (int sp = 0; sp < 2; ++sp) {
      float bacc[8] = {0.f, 0.f, 0.f, 0.f, 0.f, 0.f, 0.f, 0.f};
      const float4 ra =
          *reinterpret_cast<const float4*>(&ro_[768 + LCl + sp * 8]);
      const float4 rb =
          *reinterpret_cast<const float4*>(&ro_[768 + LCl + sp * 8 + 4]);
#pragma unroll
      for (int q = 0; q < 8; ++q) {
        const int c = sp * 8 + q;
        const int s = ((c & 7) << 5) + (cg << 1) + (c >> 3);
        const int sw = s & 7;
        const float4* wc = reinterpret_cast<const float4*>(&wlds[s * 128]);
        const float4 wa = wc[(2 * rr) ^ sw];
        const float4 wb = wc[(2 * rr + 1) ^ sw];
        const float roc = (q < 4) ? (&ra.x)[q] : (&rb.x)[q - 4];
        bacc[q] = fmaf(rh8[0], wa.x, bacc[q]);
        bacc[q] = fmaf(rh8[1], wa.y, bacc[q]);
        bacc[q] = fmaf(rh8[2], wa.z, bacc[q]);
        bacc[q] = fmaf(rh8[3], wa.w, bacc[q]);
        bacc[q] = fmaf(rh8[4], wb.x, bacc[q]);
        bacc[q] = fmaf(rh8[5], wb.y, bacc[q]);
        bacc[q] = fmaf(rh8[6], wb.z, bacc[q]);
        bacc[q] = fmaf(rh8[7], wb.w, bacc[q]);
        pa[0] = fmaf(wa.x, roc, pa[0]);
        pa[1] = fmaf(wa.y, roc, pa[1]);
        pa[2] = fmaf(wa.z, roc, pa[2]);
        pa[3] = fmaf(wa.w, roc, pa[3]);
        pa[4] = fmaf(wb.x, roc, pa[4]);
        pa[5] = fmaf(wb.y, roc, pa[5]);
        pa[6] = fmaf(wb.z, roc, pa[6]);
        pa[7] = fmaf(wb.w, roc, pa[7]);
      }
#pragma unroll
      for (int q = 0; q < 8; ++q) bacc[q] = dpp_reduce16(bacc[q]);
      if (rr == 15) {
        *reinterpret_cast<float4*>(&bl_[768 + LCl + sp * 8]) =
            make_float4(bacc[0], bacc[1], bacc[2], bacc[3]);
        *reinterpret_cast<float4*>(&bl_[768 + LCl + sp * 8 + 4]) =
            make_float4(bacc[4], bacc[5], bacc[6], bacc[7]);
      }
    }
    // ---- stage a-partials ----
    *reinterpret_cast<float4*>(&ap_[cg][8 * rr]) =
        make_float4(pa[0], pa[1], pa[2], pa[3]);
    *reinterpret_cast<float4*>(&ap_[cg][8 * rr + 4]) =
        make_float4(pa[4], pa[5], pa[6], pa[7]);
    __syncthreads();  // bl_/ap_ valid; ro_/rh_ free to rewrite
    // ---- o-update: thread owns cols t+256q ----
#pragma unroll
    for (int q = 0; q < 4; ++q) {
      const float bs = bl_[t + 256 * q];
      const float rot = rho(ov[q]);
      const float go = drho(ov[q]) * (rot - b2v[q] - bs);
      mo[q] = 0.9f * mo[q] + 0.1f * go;
      vo[q] = 0.999f * vo[q] + 0.001f * (go * go);
      ov[q] -= 0.01f * (mo[q] / bc1) / (sqrtf(vo[q] / bc2) + 1e-8f);
      ro_[t + 256 * q] = rho(ov[q]);
    }
    // ---- h-update: thread t<128 owns row t ----
    if (t < 128) {
      float a0 = 0.f, a1 = 0.f, a2 = 0.f, a3 = 0.f;
#pragma unroll
      for (int q = 0; q < 16; q += 4) {
        a0 += ap_[q + 0][t];
        a1 += ap_[q + 1][t];
        a2 += ap_[q + 2][t];
        a3 += ap_[q + 3][t];
      }
      const float a = (a0 + a1) + (a2 + a3);
      const float rold = rho(hreg);
      const float gh = drho(hreg) * (rold - b1v - c0v - a);
      mh = 0.9f * mh + 0.1f * gh;
      vh = 0.999f * vh + 0.001f * (gh * gh);
      hreg -= 0.01f * (mh / bc1) / (sqrtf(vh / bc2) + 1e-8f);
      rh_[t] = rho(hreg);
    }
    __syncthreads();  // rh_/ro_ updated for next pass
  }
#pragma unroll
  for (int q = 0; q < 4; ++q) out[t + 256 * q] = ov[q];
}

extern "C" void kernel_launch(void* const* d_in, const int* in_sizes, int n_in,
                              void* d_out, int out_size, void* d_ws,
                              size_t ws_size, hipStream_t stream) {
  const float* x  = (const float*)d_in[0];
  // d_in[1] = b0: constant in E w.r.t. (h,o) -> never needed
  const float* b1 = (const float*)d_in[2];
  const float* b2 = (const float*)d_in[3];
  const float* W0 = (const float*)d_in[4];
  const float* W1 = (const float*)d_in[5];
  const int*   ni = (const int*)d_in[6];
  float* out = (float*)d_out;

  char* ws = (char*)d_ws;
  float* part2 = (float*)ws;             // <=32 x 128 f32 = 16 KB
  float* part1 = (float*)(ws + 16384);

  const int nrows = in_sizes[0];  // 262144
  const size_t hdr = 16384;
  int nblk1;
  if (ws_size >= hdr + (size_t)(nrows / 256) * 512) {
    nblk1 = nrows / 256;  // 1024 blocks
    hipLaunchKernelGGL(k1_xw0<256>, dim3(nblk1), dim3(256), 0, stream,
                       x, W0, W1, part1);
  } else if (ws_size >= hdr + (size_t)(nrows / 512) * 512) {
    nblk1 = nrows / 512;
    hipLaunchKernelGGL(k1_xw0<512>, dim3(nblk1), dim3(256), 0, stream,
                       x, W0, W1, part1);
  } else {
    nblk1 = nrows / 1024;
    hipLaunchKernelGGL(k1_xw0<1024>, dim3(nblk1), dim3(256), 0, stream,
                       x, W0, W1, part1);
  }
  const int nblk2 = nblk1 / 32;
  hipLaunchKernelGGL(k1b_reduce, dim3(nblk2), dim3(256), 0, stream,
                     part1, part2);
  hipLaunchKernelGGL(k2_iter, dim3(1), dim3(256), 0, stream,
                     part2, nblk2, W1, b1, b2, ni, out);
}